// Round 4
// baseline (341.880 us; speedup 1.0000x reference)
//
#include <hip/hip_runtime.h>

// Problem constants (fixed by the reference: shape (20,1,128,128,128) fp32)
#define NBATCH 20
#define ELEMS_PER_BATCH (128 * 128 * 128)       // 2,097,152
#define BLOCKS_PER_BATCH 128
#define THREADS 256
#define V4_PER_THREAD 16                        // 128 blk * 256 thr * 16 * 4 = 2,097,152
#define NPART (NBATCH * BLOCKS_PER_BATCH)       // 2560 partials
#define STAGE 8                                 // float4-pairs pinned per sched_barrier window

#define LN2 0.69314718055994530942
// torch clamps log at -100 -> in log2 space: -100/ln2
#define LOG2_CLAMP (-144.26950408889634f)

// Round-3 evidence: dur identical (118 us) whether inputs are HBM- or
// L3-resident -> NOT HBM-bound; latency-bound with ~2 loads in flight
// (VGPR=36: the scheduler dissolved the source-level staging to cut
// pressure). Fix: pin the 16-load window with sched_barrier(0), which both
// pre-RA and post-RA schedulers must not cross, forcing real registers for
// all 16 dwordx4 (16 KB/wave in flight) and partial vmcnt waits.
__global__ __launch_bounds__(THREADS, 4) void partial_kernel(
    const float* __restrict__ x, const float* __restrict__ y,
    float* __restrict__ bce_part, int* __restrict__ pred_part,
    int* __restrict__ true_part) {
  const int b   = blockIdx.y;
  const int seg = blockIdx.x;
  const int tid = threadIdx.x;

  const long base4 = (long)b * (ELEMS_PER_BATCH / 4) +
                     (long)seg * (THREADS * V4_PER_THREAD);
  const float4* __restrict__ x4 = (const float4*)x;
  const float4* __restrict__ y4 = (const float4*)y;

  float bce0 = 0.0f, bce1 = 0.0f, bce2c = 0.0f, bce3 = 0.0f;  // 4 chains
  int pc = 0, tc = 0;

#pragma unroll
  for (int o = 0; o < V4_PER_THREAD / STAGE; ++o) {
    float4 xa[STAGE], ya[STAGE];
#pragma unroll
    for (int j = 0; j < STAGE; ++j) {
      xa[j] = x4[base4 + (long)(o * STAGE + j) * THREADS + tid];
    }
#pragma unroll
    for (int j = 0; j < STAGE; ++j) {
      ya[j] = y4[base4 + (long)(o * STAGE + j) * THREADS + tid];
    }
    // Hard scheduling fence: nothing (including these loads) may be moved
    // across this point by the machine schedulers.
    __builtin_amdgcn_sched_barrier(0);

#pragma unroll
    for (int j = 0; j < STAGE; ++j) {
      const float4 xv = xa[j];
      const float4 yv = ya[j];
#pragma unroll
      for (int c = 0; c < 4; ++c) {
        const float xx = (c == 0) ? xv.x : (c == 1) ? xv.y : (c == 2) ? xv.z : xv.w;
        const float yy = (c == 0) ? yv.x : (c == 1) ? yv.y : (c == 2) ? yv.z : yv.w;
        const float lx = fmaxf(__builtin_amdgcn_logf(xx),        LOG2_CLAMP);
        const float l1 = fmaxf(__builtin_amdgcn_logf(1.0f - xx), LOG2_CLAMP);
        // y*lx + (1-y)*l1 = l1 + y*(lx - l1)
        const float t = l1 + yy * (lx - l1);
        if (c == 0) bce0 += t; else if (c == 1) bce1 += t;
        else if (c == 2) bce2c += t; else bce3 += t;
        pc += (xx <= 0.5f);
        tc += (yy < 1.0f);
      }
    }
  }

  const float bce = (bce0 + bce1) + (bce2c + bce3);

  __shared__ float sb[THREADS];
  __shared__ int   sp[THREADS];
  __shared__ int   st[THREADS];
  sb[tid] = bce; sp[tid] = pc; st[tid] = tc;
  __syncthreads();
#pragma unroll
  for (int s = THREADS / 2; s > 0; s >>= 1) {
    if (tid < s) {
      sb[tid] += sb[tid + s];
      sp[tid] += sp[tid + s];
      st[tid] += st[tid + s];
    }
    __syncthreads();
  }
  if (tid == 0) {
    const int o = b * BLOCKS_PER_BATCH + seg;
    bce_part[o]  = (float)(sb[0] * LN2);  // back to natural-log units
    pred_part[o] = sp[0];
    true_part[o] = st[0];
  }
}

// Kernel 2: single block. Double-precision BCE total; per-batch POR; compose.
__global__ __launch_bounds__(THREADS) void final_kernel(
    const float* __restrict__ bce_part, const int* __restrict__ pred_part,
    const int* __restrict__ true_part, float* __restrict__ out) {
  const int tid = threadIdx.x;
  __shared__ double sred[THREADS];
  __shared__ float  spor[NBATCH];

  double local = 0.0;
  for (int i = tid; i < NPART; i += THREADS) local += (double)bce_part[i];
  sred[tid] = local;
  __syncthreads();
#pragma unroll
  for (int s = THREADS / 2; s > 0; s >>= 1) {
    if (tid < s) sred[tid] += sred[tid + s];
    __syncthreads();
  }

  if (tid < NBATCH) {
    int pc = 0, tc = 0;
    for (int k = 0; k < BLOCKS_PER_BATCH; ++k) {
      pc += pred_part[tid * BLOCKS_PER_BATCH + k];
      tc += true_part[tid * BLOCKS_PER_BATCH + k];
    }
    const float pp = (float)pc / (float)ELEMS_PER_BATCH;
    const float pt = (float)tc / (float)ELEMS_PER_BATCH;
    const float d = pp - pt;
    spor[tid] = d * d;
  }
  __syncthreads();

  if (tid == 0) {
    float pore_sum = 0.0f;
#pragma unroll
    for (int b = 0; b < NBATCH; ++b) pore_sum += spor[b];
    const float pore = pore_sum / (float)NBATCH;
    const double total = (double)NBATCH * (double)ELEMS_PER_BATCH;
    const float mse = (float)(-(sred[0] / total));
    out[0] = pore + mse;
    out[1] = pore;
  }
}

extern "C" void kernel_launch(void* const* d_in, const int* in_sizes, int n_in,
                              void* d_out, int out_size, void* d_ws, size_t ws_size,
                              hipStream_t stream) {
  const float* x = (const float*)d_in[0];
  const float* y = (const float*)d_in[1];
  float* out = (float*)d_out;

  // Workspace layout: [NPART floats][NPART ints][NPART ints] — every slot is
  // fully overwritten by partial_kernel, so no init needed despite 0xAA poison.
  float* bce_part  = (float*)d_ws;
  int*   pred_part = (int*)(bce_part + NPART);
  int*   true_part = pred_part + NPART;

  dim3 grid(BLOCKS_PER_BATCH, NBATCH);
  partial_kernel<<<grid, THREADS, 0, stream>>>(x, y, bce_part, pred_part, true_part);
  final_kernel<<<1, THREADS, 0, stream>>>(bce_part, pred_part, true_part, out);
}

// Round 5
// 339.122 us; speedup vs baseline: 1.0081x; 1.0081x over previous
//
#include <hip/hip_runtime.h>

// Problem constants (fixed by the reference: shape (20,1,128,128,128) fp32)
#define NBATCH 20
#define EPB (128 * 128 * 128)                   // 2,097,152 elems per batch
#define BLOCKS_PER_BATCH 128
#define THREADS 256
#define NSTAGE 16                               // float4s per thread per array
#define NSLOT 4                                 // LDS ring depth (3-ahead prefetch)
#define NPART (NBATCH * BLOCKS_PER_BATCH)

#define LN2 0.69314718055994530942
#define LOG2_CLAMP (-144.26950408889634f)       // -100/ln2

// s_waitcnt imm (gfx9): vmcnt[3:0]+[15:14], expcnt[6:4]=7, lgkmcnt[11:8]=0xF
#define WAITVM(n) __builtin_amdgcn_s_waitcnt(0xF70 | ((n) & 0xF) | (((n) & 0x30) << 10))

typedef const __attribute__((address_space(1))) void* gas1_t;
typedef __attribute__((address_space(3))) void* las3_t;
// 16B-wide global->LDS DMA: lane i deposits at ldsbase + i*16 (wave-uniform base).
#define GLD_LDS16(gp, lp) \
  __builtin_amdgcn_global_load_lds((gas1_t)(const void*)(gp), (las3_t)(void*)(lp), 16, 0, 0)

// R4 evidence: VGPR-staged pipelines (24/36/48 VGPR variants) all hit the same
// ~119 us floor; L3-resident replays identical -> in-flight-bytes starved, and
// the register allocator keeps collapsing VGPR staging. Fix: LDS-DMA staging —
// in-flight data lives in the global_load_lds queue, not VGPRs, so the
// allocator can't dissolve it. Per-wave private 4-slot ring, depth-3 prefetch,
// fine-grained vmcnt (never 0 in steady state), no __syncthreads in the loop.
__global__ __launch_bounds__(THREADS) void partial_kernel(
    const float* __restrict__ x, const float* __restrict__ y,
    float* __restrict__ bce_part, int* __restrict__ pred_part,
    int* __restrict__ true_part) {
  __shared__ float4 xs[4][NSLOT][64];   // [wave][slot][lane] 16 KB
  __shared__ float4 ys[4][NSLOT][64];   // 16 KB
  __shared__ float  sb[THREADS];
  __shared__ int    sp[THREADS];
  __shared__ int    st[THREADS];

  const int b    = blockIdx.y;
  const int seg  = blockIdx.x;
  const int tid  = threadIdx.x;
  const int wave = tid >> 6;
  const int lane = tid & 63;

  const long base4 = (long)b * (EPB / 4) + (long)seg * (THREADS * NSTAGE);
  const float4* __restrict__ x4 = (const float4*)x;
  const float4* __restrict__ y4 = (const float4*)y;
  // Stage s, this thread's float4: base4 + s*THREADS + wave*64 + lane.
  // Wave's 64 lanes are contiguous -> contiguous 1 KB LDS deposit per DMA.
  const long wbase = base4 + (long)wave * 64 + lane;

  // Preload stages 0..2 (6 DMAs in flight).
#pragma unroll
  for (int s = 0; s < NSLOT - 1; ++s) {
    GLD_LDS16(x4 + wbase + (long)s * THREADS, &xs[wave][s][0]);
    GLD_LDS16(y4 + wbase + (long)s * THREADS, &ys[wave][s][0]);
  }

  float bce0 = 0.0f, bce1 = 0.0f, bce2 = 0.0f, bce3 = 0.0f;
  int pc = 0, tc = 0;

  // WAITVM needs a literal -> hand-unrolled stage macro. Wait value: in steady
  // state 6 outstanding DMAs remain (stages s+1..s+3); tail ramps 4,2,0.
#define STAGE(S)                                                               \
  do {                                                                         \
    if ((S) + NSLOT - 1 < NSTAGE) {                                            \
      GLD_LDS16(x4 + wbase + (long)((S) + 3) * THREADS,                        \
                &xs[wave][((S) + 3) & 3][0]);                                  \
      GLD_LDS16(y4 + wbase + (long)((S) + 3) * THREADS,                        \
                &ys[wave][((S) + 3) & 3][0]);                                  \
    }                                                                          \
    WAITVM((2 * (NSTAGE - 1 - (S)) < 6) ? 2 * (NSTAGE - 1 - (S)) : 6);         \
    __builtin_amdgcn_sched_barrier(0);                                         \
    {                                                                          \
      const float4 xv = xs[wave][(S) & 3][lane];                               \
      const float4 yv = ys[wave][(S) & 3][lane];                               \
      _Pragma("unroll") for (int c = 0; c < 4; ++c) {                          \
        const float xx = (c == 0) ? xv.x : (c == 1) ? xv.y                     \
                                  : (c == 2) ? xv.z : xv.w;                    \
        const float yy = (c == 0) ? yv.x : (c == 1) ? yv.y                     \
                                  : (c == 2) ? yv.z : yv.w;                    \
        const float lx = fmaxf(__builtin_amdgcn_logf(xx),        LOG2_CLAMP);  \
        const float l1 = fmaxf(__builtin_amdgcn_logf(1.0f - xx), LOG2_CLAMP);  \
        const float t  = l1 + yy * (lx - l1);                                  \
        if (c == 0) bce0 += t; else if (c == 1) bce1 += t;                     \
        else if (c == 2) bce2 += t; else bce3 += t;                            \
        pc += (xx <= 0.5f);                                                    \
        tc += (yy < 1.0f);                                                     \
      }                                                                        \
    }                                                                          \
  } while (0)

  STAGE(0);  STAGE(1);  STAGE(2);  STAGE(3);
  STAGE(4);  STAGE(5);  STAGE(6);  STAGE(7);
  STAGE(8);  STAGE(9);  STAGE(10); STAGE(11);
  STAGE(12); STAGE(13); STAGE(14); STAGE(15);
#undef STAGE

  const float bce = (bce0 + bce1) + (bce2 + bce3);

  sb[tid] = bce; sp[tid] = pc; st[tid] = tc;
  __syncthreads();
#pragma unroll
  for (int s = THREADS / 2; s > 0; s >>= 1) {
    if (tid < s) {
      sb[tid] += sb[tid + s];
      sp[tid] += sp[tid + s];
      st[tid] += st[tid + s];
    }
    __syncthreads();
  }
  if (tid == 0) {
    const int o = b * BLOCKS_PER_BATCH + seg;
    bce_part[o]  = (float)(sb[0] * LN2);  // log2 -> natural-log units
    pred_part[o] = sp[0];
    true_part[o] = st[0];
  }
}

// Kernel 2: single block. Double-precision BCE total; per-batch POR; compose.
__global__ __launch_bounds__(THREADS) void final_kernel(
    const float* __restrict__ bce_part, const int* __restrict__ pred_part,
    const int* __restrict__ true_part, float* __restrict__ out) {
  const int tid = threadIdx.x;
  __shared__ double sred[THREADS];
  __shared__ float  spor[NBATCH];

  double local = 0.0;
  for (int i = tid; i < NPART; i += THREADS) local += (double)bce_part[i];
  sred[tid] = local;
  __syncthreads();
#pragma unroll
  for (int s = THREADS / 2; s > 0; s >>= 1) {
    if (tid < s) sred[tid] += sred[tid + s];
    __syncthreads();
  }

  if (tid < NBATCH) {
    int pc = 0, tc = 0;
    for (int k = 0; k < BLOCKS_PER_BATCH; ++k) {
      pc += pred_part[tid * BLOCKS_PER_BATCH + k];
      tc += true_part[tid * BLOCKS_PER_BATCH + k];
    }
    const float pp = (float)pc / (float)EPB;
    const float pt = (float)tc / (float)EPB;
    const float d = pp - pt;
    spor[tid] = d * d;
  }
  __syncthreads();

  if (tid == 0) {
    float pore_sum = 0.0f;
#pragma unroll
    for (int bb = 0; bb < NBATCH; ++bb) pore_sum += spor[bb];
    const float pore = pore_sum / (float)NBATCH;
    const double total = (double)NBATCH * (double)EPB;
    const float mse = (float)(-(sred[0] / total));
    out[0] = pore + mse;
    out[1] = pore;
  }
}

extern "C" void kernel_launch(void* const* d_in, const int* in_sizes, int n_in,
                              void* d_out, int out_size, void* d_ws, size_t ws_size,
                              hipStream_t stream) {
  const float* x = (const float*)d_in[0];
  const float* y = (const float*)d_in[1];
  float* out = (float*)d_out;

  // Workspace: [NPART floats][NPART ints][NPART ints] — fully overwritten,
  // no init needed despite 0xAA poison.
  float* bce_part  = (float*)d_ws;
  int*   pred_part = (int*)(bce_part + NPART);
  int*   true_part = pred_part + NPART;

  dim3 grid(BLOCKS_PER_BATCH, NBATCH);
  partial_kernel<<<grid, THREADS, 0, stream>>>(x, y, bce_part, pred_part, true_part);
  final_kernel<<<1, THREADS, 0, stream>>>(bce_part, pred_part, true_part, out);
}